// Round 1
// baseline (226.575 us; speedup 1.0000x reference)
//
#include <hip/hip_runtime.h>

#define N_NODES 100000
#define N_EDGES 1200000
#define R_BUCKETS 256
#define RSZ 400              // 256 * 400 = 102400 >= N
#define CAP 8192             // per-bucket segment capacity (mean 4688 -> safe)
#define CH 4096
#define NC 293               // ceil(1200000 / 4096)

typedef _Float16 h8 __attribute__((ext_vector_type(8)));
typedef float f32x16 __attribute__((ext_vector_type(16)));

// ================= CSR build: segmented buckets, packed 32-bit edge records =================
// S1: per-chunk LDS histogram -> one global atomicAdd per (chunk,bucket) -> LDS-ticket scatter
// Edge record: (src << 9) | (dst - bucket*RSZ)   [src < 2^17, local d < 512]
__global__ __launch_bounds__(256) void bkt_scatter(const int* __restrict__ src,
                                                   const int* __restrict__ dst,
                                                   int* __restrict__ bucket_alloc,
                                                   int* __restrict__ ebuf, int E) {
    __shared__ int h[R_BUCKETS];
    __shared__ int off[R_BUCKETS];
    h[threadIdx.x] = 0;
    __syncthreads();
    int e0 = blockIdx.x * CH;
    int e1 = min(e0 + CH, E);
    for (int e = e0 + (int)threadIdx.x; e < e1; e += 256)
        atomicAdd(&h[dst[e] / RSZ], 1);
    __syncthreads();
    int b = threadIdx.x;
    int hc = h[b];
    off[b] = b * CAP + (hc > 0 ? atomicAdd(&bucket_alloc[b], hc) : 0);
    __syncthreads();
    for (int e = e0 + (int)threadIdx.x; e < e1; e += 256) {
        int d = dst[e];
        int bk = d / RSZ;
        int p = atomicAdd(&off[bk], 1);
        ebuf[p] = (src[e] << 9) | (d - bk * RSZ);
    }
}

// S2: per-bucket (256 blocks): LDS hist -> dinv, LDS scan -> row2, ticket pass -> csr
__global__ __launch_bounds__(256) void bkt_build(const int* __restrict__ ebuf,
                                                 const int* __restrict__ bcnt,
                                                 int2* __restrict__ row2,
                                                 float* __restrict__ dinv,
                                                 int* __restrict__ csr, int N) {
    __shared__ int hist[RSZ];
    __shared__ int pref[RSZ];
    __shared__ int part[256];
    int r = blockIdx.x;
    int nbase = r * RSZ;
    int ebase = r * CAP;
    int ecnt = bcnt[r];
    for (int i = threadIdx.x; i < RSZ; i += 256) hist[i] = 0;
    __syncthreads();
    for (int e = (int)threadIdx.x; e < ecnt; e += 256)
        atomicAdd(&hist[ebuf[ebase + e] & 511], 1);
    __syncthreads();
    for (int i = threadIdx.x; i < RSZ; i += 256) {
        int gi = nbase + i;
        if (gi < N) dinv[gi] = rsqrtf((float)hist[i] + 1.0f);  // +1 self loop
    }
    // exclusive scan of hist (2 bins/thread; RSZ=400 even)
    int s0 = threadIdx.x * 2;
    int sum = (s0 < RSZ) ? hist[s0] + hist[s0 + 1] : 0;
    part[threadIdx.x] = sum;
    __syncthreads();
    for (int off = 1; off < 256; off <<= 1) {
        int v = (threadIdx.x >= off) ? part[threadIdx.x - off] : 0;
        __syncthreads();
        part[threadIdx.x] += v;
        __syncthreads();
    }
    if (s0 < RSZ) {
        int run = part[threadIdx.x] - sum;
        pref[s0] = run;
        pref[s0 + 1] = run + hist[s0];
    }
    __syncthreads();
    for (int i = threadIdx.x; i < RSZ; i += 256) {
        int gi = nbase + i;
        if (gi < N) row2[gi] = make_int2(ebase + pref[i], ebase + pref[i] + hist[i]);
    }
    __syncthreads();
    for (int e = (int)threadIdx.x; e < ecnt; e += 256) {
        int epk = ebuf[ebase + e];
        int t = atomicAdd(&pref[epk & 511], 1);
        csr[ebase + t] = (int)(((unsigned)epk) >> 9);
    }
}

// ============ prep: w2l = W2@Wl (block 32) + W1 split-fp16 B-fragments (blocks 0..31) ============
__global__ void prep_kernel(const float* __restrict__ W1, const float* __restrict__ W2,
                            const float* __restrict__ Wl, float* __restrict__ w2l,
                            _Float16* __restrict__ whi, _Float16* __restrict__ wlo) {
    if (blockIdx.x == 32) {
        if (threadIdx.x < 64) {
            int f = threadIdx.x;
            float s = 0.0f;
            for (int o = 0; o < 64; o++) s += W2[f * 64 + o] * Wl[o];
            w2l[f] = s;
        }
        return;
    }
    int idx = blockIdx.x * 256 + threadIdx.x;  // 2*8*64*8 = 8192
    int j = idx & 7;
    int lane = (idx >> 3) & 63;
    int kk = (idx >> 9) & 7;
    int nt = idx >> 12;
    int k = kk * 16 + (lane >> 5) * 8 + j;
    int n = nt * 32 + (lane & 31);
    float v = W1[k * 64 + n];
    _Float16 hi = (_Float16)v;
    whi[idx] = hi;
    wlo[idx] = (_Float16)(v - (float)hi);
}

// ===== MFMA GEMM: t1[i,:] = fp16( dinv[i] * (X[i,:] @ W1) ), split-fp16 accuracy =====
__global__ __launch_bounds__(256) void gemm_mfma(const float* __restrict__ x,
                                                 const _Float16* __restrict__ whi,
                                                 const _Float16* __restrict__ wlo,
                                                 const float* __restrict__ dinv,
                                                 _Float16* __restrict__ out, int N) {
    int wave = threadIdx.x >> 6;
    int lane = threadIdx.x & 63;
    int base = blockIdx.x * 128 + wave * 32;
    int row = base + (lane & 31);
    int rowc = min(row, N - 1);
    const float* xrow = x + (size_t)rowc * 128 + (lane >> 5) * 8;

    f32x16 acc0, acc1;
#pragma unroll
    for (int i = 0; i < 16; i++) { acc0[i] = 0.f; acc1[i] = 0.f; }

#pragma unroll
    for (int kk = 0; kk < 8; kk++) {
        float4 xa = *reinterpret_cast<const float4*>(xrow + kk * 16);
        float4 xb = *reinterpret_cast<const float4*>(xrow + kk * 16 + 4);
        float xv[8] = {xa.x, xa.y, xa.z, xa.w, xb.x, xb.y, xb.z, xb.w};
        h8 ahi, alo;
#pragma unroll
        for (int j = 0; j < 8; j++) {
            _Float16 hi = (_Float16)xv[j];
            ahi[j] = hi;
            alo[j] = (_Float16)(xv[j] - (float)hi);
        }
        h8 b0h = *reinterpret_cast<const h8*>(whi + (size_t)(kk * 64 + lane) * 8);
        h8 b0l = *reinterpret_cast<const h8*>(wlo + (size_t)(kk * 64 + lane) * 8);
        h8 b1h = *reinterpret_cast<const h8*>(whi + (size_t)((8 + kk) * 64 + lane) * 8);
        h8 b1l = *reinterpret_cast<const h8*>(wlo + (size_t)((8 + kk) * 64 + lane) * 8);
        acc0 = __builtin_amdgcn_mfma_f32_32x32x16_f16(ahi, b0h, acc0, 0, 0, 0);
        acc0 = __builtin_amdgcn_mfma_f32_32x32x16_f16(ahi, b0l, acc0, 0, 0, 0);
        acc0 = __builtin_amdgcn_mfma_f32_32x32x16_f16(alo, b0h, acc0, 0, 0, 0);
        acc1 = __builtin_amdgcn_mfma_f32_32x32x16_f16(ahi, b1h, acc1, 0, 0, 0);
        acc1 = __builtin_amdgcn_mfma_f32_32x32x16_f16(ahi, b1l, acc1, 0, 0, 0);
        acc1 = __builtin_amdgcn_mfma_f32_32x32x16_f16(alo, b1h, acc1, 0, 0, 0);
    }

    // C/D layout: col = lane&31, row = (reg&3) + 8*(reg>>2) + 4*(lane>>5)
    int col = lane & 31;
    int rbase = base + 4 * (lane >> 5);
#pragma unroll
    for (int reg = 0; reg < 16; reg++) {
        int node = rbase + (reg & 3) + 8 * (reg >> 2);
        if (node < N) {
            float di = dinv[node];
            out[(size_t)node * 64 + col] = (_Float16)(di * acc0[reg]);
            out[(size_t)node * 64 + 32 + col] = (_Float16)(di * acc1[reg]);
        }
    }
}

// ===== Layer-1 CSR agg, lane=feature: wave/node, 64 lane-local f32 accumulators =====
// No cross-lane feature reduction (lane f owns feature f). Edge ids splat once
// (coalesced csr load), then moved to SGPRs via readlane -> gather loads are
// SGPR-base + (lane*2) with all per-edge address math on the scalar pipe.
// Each gather = 64 lanes x 2B = exactly one 128B row / cache line.
#define AGG_NPB 32
__global__ __launch_bounds__(256) void agg1_kernel(const _Float16* __restrict__ t,
                                                   const int2* __restrict__ row2,
                                                   const int* __restrict__ csr,
                                                   const float* __restrict__ dinv,
                                                   const float* __restrict__ b1,
                                                   const float* __restrict__ w2l,
                                                   float* __restrict__ q, int N) {
    int lane = threadIdx.x & 63;
    int w = threadIdx.x >> 6;
    float b1v = b1[lane];
    float wlv = w2l[lane];
    int i0 = blockIdx.x * AGG_NPB;
    int iend = min(i0 + AGG_NPB, N);
    for (int i = i0 + w; i < iend; i += 4) {
        int2 rr = row2[i];
        int rs = rr.x, re = rr.y;
        float acc = (float)t[(size_t)i * 64 + lane];  // self loop
        for (int base = rs; base < re; base += 64) {
            int m = re - base;
            int ecl = min(m, 64);
            int idx = csr[base + min(lane, m - 1)];  // splat up to 64 edge ids
            int k = 0;
            for (; k + 4 <= ecl; k += 4) {
                int s0 = __builtin_amdgcn_readlane(idx, k);
                int s1 = __builtin_amdgcn_readlane(idx, k + 1);
                int s2 = __builtin_amdgcn_readlane(idx, k + 2);
                int s3 = __builtin_amdgcn_readlane(idx, k + 3);
                float v0 = (float)t[(size_t)s0 * 64 + lane];
                float v1 = (float)t[(size_t)s1 * 64 + lane];
                float v2 = (float)t[(size_t)s2 * 64 + lane];
                float v3 = (float)t[(size_t)s3 * 64 + lane];
                acc += (v0 + v1) + (v2 + v3);
            }
            for (; k < ecl; k++) {
                int s0 = __builtin_amdgcn_readlane(idx, k);
                acc += (float)t[(size_t)s0 * 64 + lane];
            }
        }
        float di = dinv[i];
        float h = fmaxf(di * acc + b1v, 0.f);
        float p = h * wlv;
        p += __shfl_xor(p, 1, 64);
        p += __shfl_xor(p, 2, 64);
        p += __shfl_xor(p, 4, 64);
        p += __shfl_xor(p, 8, 64);
        p += __shfl_xor(p, 16, 64);
        p += __shfl_xor(p, 32, 64);
        if (lane == 0) q[i] = di * p;
    }
}

// ================= Layer-2 scalar agg + pooled sum (batch sorted -> LDS bins) =================
__global__ __launch_bounds__(256) void agg2_pool_kernel(const float* __restrict__ q,
                                                        const int2* __restrict__ row2,
                                                        const int* __restrict__ csr,
                                                        const float* __restrict__ dinv,
                                                        const int* __restrict__ batch,
                                                        float* __restrict__ gsum, int N) {
    __shared__ float bins[256];
    bins[threadIdx.x] = 0.0f;
    __syncthreads();
    int i = blockIdx.x * 256 + threadIdx.x;
    if (i < N) {
        int2 rr = row2[i];
        float acc = q[i];  // self loop
        for (int j = rr.x; j < rr.y; j++) acc += q[csr[j]];
        atomicAdd(&bins[batch[i]], dinv[i] * acc);
    }
    __syncthreads();
    int i0 = blockIdx.x * 256;
    if (i0 < N) {
        int ilast = min(i0 + 255, N - 1);
        int gmin = batch[i0];
        int gmax = batch[ilast];
        for (int g = gmin + (int)threadIdx.x; g <= gmax; g += 256)
            atomicAdd(&gsum[g], bins[g]);
    }
}

// ---- out[g] = gsum[g]/cnt[g] + dot(b2,Wl) + bl ; cnt via binary search on sorted batch ----
__global__ void out_kernel(const float* __restrict__ gsum, const int* __restrict__ batch,
                           const float* __restrict__ b2, const float* __restrict__ Wl,
                           const float* __restrict__ bl, float* __restrict__ out, int N) {
    int g = threadIdx.x;
    int lo = 0, hi = N;
    while (lo < hi) { int m = (lo + hi) >> 1; if (batch[m] < g) lo = m + 1; else hi = m; }
    int start = lo;
    hi = N;
    while (lo < hi) { int m = (lo + hi) >> 1; if (batch[m] < g + 1) lo = m + 1; else hi = m; }
    int cnt = lo - start;
    float c = 0.0f;
    for (int f = 0; f < 64; f++) c += b2[f] * Wl[f];
    out[g] = gsum[g] / fmaxf((float)cnt, 1.0f) + c + bl[0];
}

extern "C" void kernel_launch(void* const* d_in, const int* in_sizes, int n_in,
                              void* d_out, int out_size, void* d_ws, size_t ws_size,
                              hipStream_t stream) {
    const float* x  = (const float*)d_in[0];
    const int*   ei = (const int*)d_in[1];
    const int*   batch = (const int*)d_in[2];
    const float* W1 = (const float*)d_in[3];
    const float* b1 = (const float*)d_in[4];
    const float* W2 = (const float*)d_in[5];
    const float* b2 = (const float*)d_in[6];
    const float* Wl = (const float*)d_in[7];
    const float* bl = (const float*)d_in[8];
    float* out = (float*)d_out;

    const int N = N_NODES, E = N_EDGES;
    const int nblk = (N + 255) / 256;  // 391
    const int* src = ei;
    const int* dst = ei + E;

    // workspace layout (bytes; big aligned blocks first)
    char* ws = (char*)d_ws;
    int*      ebuf      = (int*)ws;       ws += (size_t)R_BUCKETS * CAP * 4;  // 8.4 MB (packed)
    int*      csr       = (int*)ws;       ws += (size_t)R_BUCKETS * CAP * 4;  // 8.4 MB
    _Float16* buf1      = (_Float16*)ws;  ws += 6400000 * 2;                  // t1 (fp16)
    int2*     row2      = (int2*)ws;      ws += 100096 * 8;
    float*    dinv      = (float*)ws;     ws += 100096 * 4;
    float*    q         = (float*)ws;     ws += 100096 * 4;
    float*    gsum      = (float*)ws;     ws += 256 * 4;
    int*      bucket_alloc = (int*)ws;    ws += 256 * 4;
    float*    w2l       = (float*)ws;     ws += 256 * 4;
    _Float16* whi       = (_Float16*)ws;  ws += 8192 * 2;
    _Float16* wlo       = (_Float16*)ws;  ws += 8192 * 2;

    hipMemsetAsync(gsum, 0, 2048, stream);  // gsum + bucket_alloc (adjacent)

    // CSR build: segmented bucket scatter -> per-bucket build (256 blocks, no global scan)
    bkt_scatter<<<NC, 256, 0, stream>>>(src, dst, bucket_alloc, ebuf, E);
    bkt_build<<<R_BUCKETS, 256, 0, stream>>>(ebuf, bucket_alloc, row2, dinv, csr, N);

    prep_kernel<<<33, 256, 0, stream>>>(W1, W2, Wl, w2l, whi, wlo);

    // Layer 1 GEMM on matrix cores: t1 = fp16(dinv*(x@W1))
    gemm_mfma<<<(N + 127) / 128, 256, 0, stream>>>(x, whi, wlo, dinv, buf1, N);

    // Layer-1 aggregation fused with folded layer-2 GEMM -> scalar q per node
    agg1_kernel<<<(N + AGG_NPB - 1) / AGG_NPB, 256, 0, stream>>>(
        buf1, row2, csr, dinv, b1, w2l, q, N);

    // Layer-2 scalar aggregation + mean-pool numerator
    agg2_pool_kernel<<<nblk, 256, 0, stream>>>(q, row2, csr, dinv, batch, gsum, N);

    out_kernel<<<1, 256, 0, stream>>>(gsum, batch, b2, Wl, bl, out, N);
}

// Round 2
// 208.809 us; speedup vs baseline: 1.0851x; 1.0851x over previous
//
#include <hip/hip_runtime.h>

#define N_NODES 100000
#define N_EDGES 1200000
#define R_BUCKETS 256
#define RSZ 400              // 256 * 400 = 102400 >= N
#define CAP 8192             // per-bucket segment capacity (mean 4688 -> safe)
#define CH 4096
#define NC 293               // ceil(1200000 / 4096)

typedef _Float16 h8 __attribute__((ext_vector_type(8)));
typedef _Float16 h2 __attribute__((ext_vector_type(2)));
typedef float f32x16 __attribute__((ext_vector_type(16)));

// ================= CSR build: segmented buckets, packed 32-bit edge records =================
// S1: per-chunk LDS histogram -> one global atomicAdd per (chunk,bucket) -> LDS-ticket scatter
// Edge record: (src << 9) | (dst - bucket*RSZ)   [src < 2^17, local d < 512]
__global__ __launch_bounds__(256) void bkt_scatter(const int* __restrict__ src,
                                                   const int* __restrict__ dst,
                                                   int* __restrict__ bucket_alloc,
                                                   int* __restrict__ ebuf, int E) {
    __shared__ int h[R_BUCKETS];
    __shared__ int off[R_BUCKETS];
    h[threadIdx.x] = 0;
    __syncthreads();
    int e0 = blockIdx.x * CH;
    int e1 = min(e0 + CH, E);
    for (int e = e0 + (int)threadIdx.x; e < e1; e += 256)
        atomicAdd(&h[dst[e] / RSZ], 1);
    __syncthreads();
    int b = threadIdx.x;
    int hc = h[b];
    off[b] = b * CAP + (hc > 0 ? atomicAdd(&bucket_alloc[b], hc) : 0);
    __syncthreads();
    for (int e = e0 + (int)threadIdx.x; e < e1; e += 256) {
        int d = dst[e];
        int bk = d / RSZ;
        int p = atomicAdd(&off[bk], 1);
        ebuf[p] = (src[e] << 9) | (d - bk * RSZ);
    }
}

// S2: per-bucket (256 blocks): LDS hist -> dinv, LDS scan -> row2, ticket pass -> csr
__global__ __launch_bounds__(256) void bkt_build(const int* __restrict__ ebuf,
                                                 const int* __restrict__ bcnt,
                                                 int2* __restrict__ row2,
                                                 float* __restrict__ dinv,
                                                 int* __restrict__ csr, int N) {
    __shared__ int hist[RSZ];
    __shared__ int pref[RSZ];
    __shared__ int part[256];
    int r = blockIdx.x;
    int nbase = r * RSZ;
    int ebase = r * CAP;
    int ecnt = bcnt[r];
    for (int i = threadIdx.x; i < RSZ; i += 256) hist[i] = 0;
    __syncthreads();
    for (int e = (int)threadIdx.x; e < ecnt; e += 256)
        atomicAdd(&hist[ebuf[ebase + e] & 511], 1);
    __syncthreads();
    for (int i = threadIdx.x; i < RSZ; i += 256) {
        int gi = nbase + i;
        if (gi < N) dinv[gi] = rsqrtf((float)hist[i] + 1.0f);  // +1 self loop
    }
    // exclusive scan of hist (2 bins/thread; RSZ=400 even)
    int s0 = threadIdx.x * 2;
    int sum = (s0 < RSZ) ? hist[s0] + hist[s0 + 1] : 0;
    part[threadIdx.x] = sum;
    __syncthreads();
    for (int off = 1; off < 256; off <<= 1) {
        int v = (threadIdx.x >= off) ? part[threadIdx.x - off] : 0;
        __syncthreads();
        part[threadIdx.x] += v;
        __syncthreads();
    }
    if (s0 < RSZ) {
        int run = part[threadIdx.x] - sum;
        pref[s0] = run;
        pref[s0 + 1] = run + hist[s0];
    }
    __syncthreads();
    for (int i = threadIdx.x; i < RSZ; i += 256) {
        int gi = nbase + i;
        if (gi < N) row2[gi] = make_int2(ebase + pref[i], ebase + pref[i] + hist[i]);
    }
    __syncthreads();
    for (int e = (int)threadIdx.x; e < ecnt; e += 256) {
        int epk = ebuf[ebase + e];
        int t = atomicAdd(&pref[epk & 511], 1);
        csr[ebase + t] = (int)(((unsigned)epk) >> 9);
    }
}

// ============ prep: w2l = W2@Wl (block 32) + W1 split-fp16 B-fragments (blocks 0..31) ============
__global__ void prep_kernel(const float* __restrict__ W1, const float* __restrict__ W2,
                            const float* __restrict__ Wl, float* __restrict__ w2l,
                            _Float16* __restrict__ whi, _Float16* __restrict__ wlo) {
    if (blockIdx.x == 32) {
        if (threadIdx.x < 64) {
            int f = threadIdx.x;
            float s = 0.0f;
            for (int o = 0; o < 64; o++) s += W2[f * 64 + o] * Wl[o];
            w2l[f] = s;
        }
        return;
    }
    int idx = blockIdx.x * 256 + threadIdx.x;  // 2*8*64*8 = 8192
    int j = idx & 7;
    int lane = (idx >> 3) & 63;
    int kk = (idx >> 9) & 7;
    int nt = idx >> 12;
    int k = kk * 16 + (lane >> 5) * 8 + j;
    int n = nt * 32 + (lane & 31);
    float v = W1[k * 64 + n];
    _Float16 hi = (_Float16)v;
    whi[idx] = hi;
    wlo[idx] = (_Float16)(v - (float)hi);
}

// ===== MFMA GEMM: t1[i,:] = fp16( dinv[i] * (X[i,:] @ W1) ), split-fp16 accuracy =====
__global__ __launch_bounds__(256) void gemm_mfma(const float* __restrict__ x,
                                                 const _Float16* __restrict__ whi,
                                                 const _Float16* __restrict__ wlo,
                                                 const float* __restrict__ dinv,
                                                 _Float16* __restrict__ out, int N) {
    int wave = threadIdx.x >> 6;
    int lane = threadIdx.x & 63;
    int base = blockIdx.x * 128 + wave * 32;
    int row = base + (lane & 31);
    int rowc = min(row, N - 1);
    const float* xrow = x + (size_t)rowc * 128 + (lane >> 5) * 8;

    f32x16 acc0, acc1;
#pragma unroll
    for (int i = 0; i < 16; i++) { acc0[i] = 0.f; acc1[i] = 0.f; }

#pragma unroll
    for (int kk = 0; kk < 8; kk++) {
        float4 xa = *reinterpret_cast<const float4*>(xrow + kk * 16);
        float4 xb = *reinterpret_cast<const float4*>(xrow + kk * 16 + 4);
        float xv[8] = {xa.x, xa.y, xa.z, xa.w, xb.x, xb.y, xb.z, xb.w};
        h8 ahi, alo;
#pragma unroll
        for (int j = 0; j < 8; j++) {
            _Float16 hi = (_Float16)xv[j];
            ahi[j] = hi;
            alo[j] = (_Float16)(xv[j] - (float)hi);
        }
        h8 b0h = *reinterpret_cast<const h8*>(whi + (size_t)(kk * 64 + lane) * 8);
        h8 b0l = *reinterpret_cast<const h8*>(wlo + (size_t)(kk * 64 + lane) * 8);
        h8 b1h = *reinterpret_cast<const h8*>(whi + (size_t)((8 + kk) * 64 + lane) * 8);
        h8 b1l = *reinterpret_cast<const h8*>(wlo + (size_t)((8 + kk) * 64 + lane) * 8);
        acc0 = __builtin_amdgcn_mfma_f32_32x32x16_f16(ahi, b0h, acc0, 0, 0, 0);
        acc0 = __builtin_amdgcn_mfma_f32_32x32x16_f16(ahi, b0l, acc0, 0, 0, 0);
        acc0 = __builtin_amdgcn_mfma_f32_32x32x16_f16(alo, b0h, acc0, 0, 0, 0);
        acc1 = __builtin_amdgcn_mfma_f32_32x32x16_f16(ahi, b1h, acc1, 0, 0, 0);
        acc1 = __builtin_amdgcn_mfma_f32_32x32x16_f16(ahi, b1l, acc1, 0, 0, 0);
        acc1 = __builtin_amdgcn_mfma_f32_32x32x16_f16(alo, b1h, acc1, 0, 0, 0);
    }

    // C/D layout: col = lane&31, row = (reg&3) + 8*(reg>>2) + 4*(lane>>5)
    int col = lane & 31;
    int rbase = base + 4 * (lane >> 5);
#pragma unroll
    for (int reg = 0; reg < 16; reg++) {
        int node = rbase + (reg & 3) + 8 * (reg >> 2);
        if (node < N) {
            float di = dinv[node];
            out[(size_t)node * 64 + col] = (_Float16)(di * acc0[reg]);
            out[(size_t)node * 64 + 32 + col] = (_Float16)(di * acc1[reg]);
        }
    }
}

// ===== Layer-1 CSR agg: half-wave per node, lane=feature-pair, 8-deep gather =====
// 2 nodes per wave (lanes 0-31 -> node A, 32-63 -> node B). Lane hl of each half
// owns features (2hl, 2hl+1) as f32 accumulators -> NO cross-lane feature
// reduction; only a 5-level shfl_xor on the final folded scalar.
// Each gather load = 32 lanes x 4B = one 128B row-line PER HALF (2 lines/instr),
// unrolled 8 deep -> 16 lines in flight per wave (vs 4 in R1: MLP was the R1 loss).
// Edge slots padded to max(degA,degB); clamped slots re-read a hot line and are
// value-masked. Splat ids clamped to [0,N) so deg-0 garbage can't leave buf1.
#define AGG_NPB 32
__global__ __launch_bounds__(256) void agg1_kernel(const _Float16* __restrict__ t,
                                                   const int2* __restrict__ row2,
                                                   const int* __restrict__ csr,
                                                   const float* __restrict__ dinv,
                                                   const float* __restrict__ b1,
                                                   const float* __restrict__ w2l,
                                                   float* __restrict__ q, int N) {
    int lane = threadIdx.x & 63;
    int w = threadIdx.x >> 6;
    int hl = lane & 31;    // lane within half
    int hsel = lane >> 5;  // 0 = node A, 1 = node B
    float2 b1v = reinterpret_cast<const float2*>(b1)[hl];
    float2 wlv = reinterpret_cast<const float2*>(w2l)[hl];
    int i0 = blockIdx.x * AGG_NPB;
    int iend = min(i0 + AGG_NPB, N);
    for (int ip = i0 + 2 * w; ip < iend; ip += 8) {
        int iA = ip;
        int iB = ip + 1;  // may be >= iend (tail) -> degB forced to 0
        bool hasB = iB < iend;
        int2 rrA = row2[iA];
        int2 rrB = hasB ? row2[iB] : make_int2(rrA.x, rrA.x);
        int myi = hsel ? iB : iA;
        int myic = min(myi, N - 1);
        int rs = hsel ? rrB.x : rrA.x;
        int re = hsel ? rrB.y : rrA.y;
        int deg = re - rs;
        int kmax = max(rrA.y - rrA.x, rrB.y - rrB.x);
        int rlast = max(re - 1, rs);
        // self loop (features 2hl, 2hl+1 of own row)
        h2 sv = *reinterpret_cast<const h2*>(t + ((size_t)myic << 6) + (hl << 1));
        float a0 = (float)sv[0];
        float a1 = (float)sv[1];
        for (int base = 0; base < kmax; base += 32) {
            // splat up to 32 edge ids of this half's node (coalesced, clamped)
            int sp = min(csr[min(rs + base + hl, rlast)] & 0x1FFFF, N - 1);
            int kend = min(kmax - base, 32);
            for (int k = 0; k < kend; k += 8) {
                h2 vv[8];
#pragma unroll
                for (int j = 0; j < 8; j++) {
                    int s = __shfl(sp, k + j, 32);  // within-half broadcast
                    vv[j] = *reinterpret_cast<const h2*>(t + ((size_t)s << 6) + (hl << 1));
                }
#pragma unroll
                for (int j = 0; j < 8; j++) {
                    if (base + k + j < deg) {
                        a0 += (float)vv[j][0];
                        a1 += (float)vv[j][1];
                    }
                }
            }
        }
        float di = dinv[myic];
        float h0 = fmaxf(di * a0 + b1v.x, 0.f);
        float h1 = fmaxf(di * a1 + b1v.y, 0.f);
        float p = h0 * wlv.x + h1 * wlv.y;
        p += __shfl_xor(p, 1, 64);
        p += __shfl_xor(p, 2, 64);
        p += __shfl_xor(p, 4, 64);
        p += __shfl_xor(p, 8, 64);
        p += __shfl_xor(p, 16, 64);
        if (hl == 0 && myi < iend) q[myi] = di * p;
    }
}

// ================= Layer-2 scalar agg + pooled sum (batch sorted -> LDS bins) =================
__global__ __launch_bounds__(256) void agg2_pool_kernel(const float* __restrict__ q,
                                                        const int2* __restrict__ row2,
                                                        const int* __restrict__ csr,
                                                        const float* __restrict__ dinv,
                                                        const int* __restrict__ batch,
                                                        float* __restrict__ gsum, int N) {
    __shared__ float bins[256];
    bins[threadIdx.x] = 0.0f;
    __syncthreads();
    int i = blockIdx.x * 256 + threadIdx.x;
    if (i < N) {
        int2 rr = row2[i];
        float acc = q[i];  // self loop
        for (int j = rr.x; j < rr.y; j++) acc += q[csr[j]];
        atomicAdd(&bins[batch[i]], dinv[i] * acc);
    }
    __syncthreads();
    int i0 = blockIdx.x * 256;
    if (i0 < N) {
        int ilast = min(i0 + 255, N - 1);
        int gmin = batch[i0];
        int gmax = batch[ilast];
        for (int g = gmin + (int)threadIdx.x; g <= gmax; g += 256)
            atomicAdd(&gsum[g], bins[g]);
    }
}

// ---- out[g] = gsum[g]/cnt[g] + dot(b2,Wl) + bl ; cnt via binary search on sorted batch ----
__global__ void out_kernel(const float* __restrict__ gsum, const int* __restrict__ batch,
                           const float* __restrict__ b2, const float* __restrict__ Wl,
                           const float* __restrict__ bl, float* __restrict__ out, int N) {
    int g = threadIdx.x;
    int lo = 0, hi = N;
    while (lo < hi) { int m = (lo + hi) >> 1; if (batch[m] < g) lo = m + 1; else hi = m; }
    int start = lo;
    hi = N;
    while (lo < hi) { int m = (lo + hi) >> 1; if (batch[m] < g + 1) lo = m + 1; else hi = m; }
    int cnt = lo - start;
    float c = 0.0f;
    for (int f = 0; f < 64; f++) c += b2[f] * Wl[f];
    out[g] = gsum[g] / fmaxf((float)cnt, 1.0f) + c + bl[0];
}

extern "C" void kernel_launch(void* const* d_in, const int* in_sizes, int n_in,
                              void* d_out, int out_size, void* d_ws, size_t ws_size,
                              hipStream_t stream) {
    const float* x  = (const float*)d_in[0];
    const int*   ei = (const int*)d_in[1];
    const int*   batch = (const int*)d_in[2];
    const float* W1 = (const float*)d_in[3];
    const float* b1 = (const float*)d_in[4];
    const float* W2 = (const float*)d_in[5];
    const float* b2 = (const float*)d_in[6];
    const float* Wl = (const float*)d_in[7];
    const float* bl = (const float*)d_in[8];
    float* out = (float*)d_out;

    const int N = N_NODES, E = N_EDGES;
    const int nblk = (N + 255) / 256;  // 391
    const int* src = ei;
    const int* dst = ei + E;

    // workspace layout (bytes; big aligned blocks first)
    char* ws = (char*)d_ws;
    int*      ebuf      = (int*)ws;       ws += (size_t)R_BUCKETS * CAP * 4;  // 8.4 MB (packed)
    int*      csr       = (int*)ws;       ws += (size_t)R_BUCKETS * CAP * 4;  // 8.4 MB
    _Float16* buf1      = (_Float16*)ws;  ws += 6400000 * 2;                  // t1 (fp16)
    int2*     row2      = (int2*)ws;      ws += 100096 * 8;
    float*    dinv      = (float*)ws;     ws += 100096 * 4;
    float*    q         = (float*)ws;     ws += 100096 * 4;
    float*    gsum      = (float*)ws;     ws += 256 * 4;
    int*      bucket_alloc = (int*)ws;    ws += 256 * 4;
    float*    w2l       = (float*)ws;     ws += 256 * 4;
    _Float16* whi       = (_Float16*)ws;  ws += 8192 * 2;
    _Float16* wlo       = (_Float16*)ws;  ws += 8192 * 2;

    hipMemsetAsync(gsum, 0, 2048, stream);  // gsum + bucket_alloc (adjacent)

    // CSR build: segmented bucket scatter -> per-bucket build (256 blocks, no global scan)
    bkt_scatter<<<NC, 256, 0, stream>>>(src, dst, bucket_alloc, ebuf, E);
    bkt_build<<<R_BUCKETS, 256, 0, stream>>>(ebuf, bucket_alloc, row2, dinv, csr, N);

    prep_kernel<<<33, 256, 0, stream>>>(W1, W2, Wl, w2l, whi, wlo);

    // Layer 1 GEMM on matrix cores: t1 = fp16(dinv*(x@W1))
    gemm_mfma<<<(N + 127) / 128, 256, 0, stream>>>(x, whi, wlo, dinv, buf1, N);

    // Layer-1 aggregation fused with folded layer-2 GEMM -> scalar q per node
    agg1_kernel<<<(N + AGG_NPB - 1) / AGG_NPB, 256, 0, stream>>>(
        buf1, row2, csr, dinv, b1, w2l, q, N);

    // Layer-2 scalar aggregation + mean-pool numerator
    agg2_pool_kernel<<<nblk, 256, 0, stream>>>(q, row2, csr, dinv, batch, gsum, N);

    out_kernel<<<1, 256, 0, stream>>>(gsum, batch, b2, Wl, bl, out, N);
}

// Round 3
// 201.696 us; speedup vs baseline: 1.1234x; 1.0353x over previous
//
#include <hip/hip_runtime.h>

#define N_NODES 100000
#define N_EDGES 1200000
#define R_BUCKETS 256
#define RSZ 400              // 256 * 400 = 102400 >= N
#define CAP 8192             // per-bucket segment capacity (mean 4688 -> safe)
#define CH 4096
#define NC 293               // ceil(1200000 / 4096)

typedef _Float16 h8 __attribute__((ext_vector_type(8)));
typedef _Float16 h2 __attribute__((ext_vector_type(2)));
typedef float f32x16 __attribute__((ext_vector_type(16)));

// ================= CSR build: segmented buckets, packed 32-bit edge records =================
// S1: per-chunk LDS histogram -> one global atomicAdd per (chunk,bucket) -> LDS-ticket scatter
// Edge record: (src << 9) | (dst - bucket*RSZ)   [src < 2^17, local d < 512]
__global__ __launch_bounds__(256) void bkt_scatter(const int* __restrict__ src,
                                                   const int* __restrict__ dst,
                                                   int* __restrict__ bucket_alloc,
                                                   int* __restrict__ ebuf, int E) {
    __shared__ int h[R_BUCKETS];
    __shared__ int off[R_BUCKETS];
    h[threadIdx.x] = 0;
    __syncthreads();
    int e0 = blockIdx.x * CH;
    int e1 = min(e0 + CH, E);
    for (int e = e0 + (int)threadIdx.x; e < e1; e += 256)
        atomicAdd(&h[dst[e] / RSZ], 1);
    __syncthreads();
    int b = threadIdx.x;
    int hc = h[b];
    off[b] = b * CAP + (hc > 0 ? atomicAdd(&bucket_alloc[b], hc) : 0);
    __syncthreads();
    for (int e = e0 + (int)threadIdx.x; e < e1; e += 256) {
        int d = dst[e];
        int bk = d / RSZ;
        int p = atomicAdd(&off[bk], 1);
        ebuf[p] = (src[e] << 9) | (d - bk * RSZ);
    }
}

// S2: per-bucket (256 blocks): LDS hist -> dinv, LDS scan -> row2, ticket pass -> csr
__global__ __launch_bounds__(256) void bkt_build(const int* __restrict__ ebuf,
                                                 const int* __restrict__ bcnt,
                                                 int2* __restrict__ row2,
                                                 float* __restrict__ dinv,
                                                 int* __restrict__ csr, int N) {
    __shared__ int hist[RSZ];
    __shared__ int pref[RSZ];
    __shared__ int part[256];
    int r = blockIdx.x;
    int nbase = r * RSZ;
    int ebase = r * CAP;
    int ecnt = bcnt[r];
    for (int i = threadIdx.x; i < RSZ; i += 256) hist[i] = 0;
    __syncthreads();
    for (int e = (int)threadIdx.x; e < ecnt; e += 256)
        atomicAdd(&hist[ebuf[ebase + e] & 511], 1);
    __syncthreads();
    for (int i = threadIdx.x; i < RSZ; i += 256) {
        int gi = nbase + i;
        if (gi < N) dinv[gi] = rsqrtf((float)hist[i] + 1.0f);  // +1 self loop
    }
    // exclusive scan of hist (2 bins/thread; RSZ=400 even)
    int s0 = threadIdx.x * 2;
    int sum = (s0 < RSZ) ? hist[s0] + hist[s0 + 1] : 0;
    part[threadIdx.x] = sum;
    __syncthreads();
    for (int off = 1; off < 256; off <<= 1) {
        int v = (threadIdx.x >= off) ? part[threadIdx.x - off] : 0;
        __syncthreads();
        part[threadIdx.x] += v;
        __syncthreads();
    }
    if (s0 < RSZ) {
        int run = part[threadIdx.x] - sum;
        pref[s0] = run;
        pref[s0 + 1] = run + hist[s0];
    }
    __syncthreads();
    for (int i = threadIdx.x; i < RSZ; i += 256) {
        int gi = nbase + i;
        if (gi < N) row2[gi] = make_int2(ebase + pref[i], ebase + pref[i] + hist[i]);
    }
    __syncthreads();
    for (int e = (int)threadIdx.x; e < ecnt; e += 256) {
        int epk = ebuf[ebase + e];
        int t = atomicAdd(&pref[epk & 511], 1);
        csr[ebase + t] = (int)(((unsigned)epk) >> 9);
    }
}

// ============ prep: w2l = W2@Wl (block 32) + W1 split-fp16 B-fragments (blocks 0..31) ============
__global__ void prep_kernel(const float* __restrict__ W1, const float* __restrict__ W2,
                            const float* __restrict__ Wl, float* __restrict__ w2l,
                            _Float16* __restrict__ whi, _Float16* __restrict__ wlo) {
    if (blockIdx.x == 32) {
        if (threadIdx.x < 64) {
            int f = threadIdx.x;
            float s = 0.0f;
            for (int o = 0; o < 64; o++) s += W2[f * 64 + o] * Wl[o];
            w2l[f] = s;
        }
        return;
    }
    int idx = blockIdx.x * 256 + threadIdx.x;  // 2*8*64*8 = 8192
    int j = idx & 7;
    int lane = (idx >> 3) & 63;
    int kk = (idx >> 9) & 7;
    int nt = idx >> 12;
    int k = kk * 16 + (lane >> 5) * 8 + j;
    int n = nt * 32 + (lane & 31);
    float v = W1[k * 64 + n];
    _Float16 hi = (_Float16)v;
    whi[idx] = hi;
    wlo[idx] = (_Float16)(v - (float)hi);
}

// ===== MFMA GEMM: t1[i,:] = fp16( dinv[i] * (X[i,:] @ W1) ), split-fp16 accuracy =====
__global__ __launch_bounds__(256) void gemm_mfma(const float* __restrict__ x,
                                                 const _Float16* __restrict__ whi,
                                                 const _Float16* __restrict__ wlo,
                                                 const float* __restrict__ dinv,
                                                 _Float16* __restrict__ out, int N) {
    int wave = threadIdx.x >> 6;
    int lane = threadIdx.x & 63;
    int base = blockIdx.x * 128 + wave * 32;
    int row = base + (lane & 31);
    int rowc = min(row, N - 1);
    const float* xrow = x + (size_t)rowc * 128 + (lane >> 5) * 8;

    f32x16 acc0, acc1;
#pragma unroll
    for (int i = 0; i < 16; i++) { acc0[i] = 0.f; acc1[i] = 0.f; }

#pragma unroll
    for (int kk = 0; kk < 8; kk++) {
        float4 xa = *reinterpret_cast<const float4*>(xrow + kk * 16);
        float4 xb = *reinterpret_cast<const float4*>(xrow + kk * 16 + 4);
        float xv[8] = {xa.x, xa.y, xa.z, xa.w, xb.x, xb.y, xb.z, xb.w};
        h8 ahi, alo;
#pragma unroll
        for (int j = 0; j < 8; j++) {
            _Float16 hi = (_Float16)xv[j];
            ahi[j] = hi;
            alo[j] = (_Float16)(xv[j] - (float)hi);
        }
        h8 b0h = *reinterpret_cast<const h8*>(whi + (size_t)(kk * 64 + lane) * 8);
        h8 b0l = *reinterpret_cast<const h8*>(wlo + (size_t)(kk * 64 + lane) * 8);
        h8 b1h = *reinterpret_cast<const h8*>(whi + (size_t)((8 + kk) * 64 + lane) * 8);
        h8 b1l = *reinterpret_cast<const h8*>(wlo + (size_t)((8 + kk) * 64 + lane) * 8);
        acc0 = __builtin_amdgcn_mfma_f32_32x32x16_f16(ahi, b0h, acc0, 0, 0, 0);
        acc0 = __builtin_amdgcn_mfma_f32_32x32x16_f16(ahi, b0l, acc0, 0, 0, 0);
        acc0 = __builtin_amdgcn_mfma_f32_32x32x16_f16(alo, b0h, acc0, 0, 0, 0);
        acc1 = __builtin_amdgcn_mfma_f32_32x32x16_f16(ahi, b1h, acc1, 0, 0, 0);
        acc1 = __builtin_amdgcn_mfma_f32_32x32x16_f16(ahi, b1l, acc1, 0, 0, 0);
        acc1 = __builtin_amdgcn_mfma_f32_32x32x16_f16(alo, b1h, acc1, 0, 0, 0);
    }

    // C/D layout: col = lane&31, row = (reg&3) + 8*(reg>>2) + 4*(lane>>5)
    int col = lane & 31;
    int rbase = base + 4 * (lane >> 5);
#pragma unroll
    for (int reg = 0; reg < 16; reg++) {
        int node = rbase + (reg & 3) + 8 * (reg >> 2);
        if (node < N) {
            float di = dinv[node];
            out[(size_t)node * 64 + col] = (_Float16)(di * acc0[reg]);
            out[(size_t)node * 64 + 32 + col] = (_Float16)(di * acc1[reg]);
        }
    }
}

// ===== Layer-1 CSR agg: half-wave per node, lane=feature-pair, 16-deep gather =====
// 2 nodes per wave (lanes 0-31 -> node A, 32-63 -> node B). Lane hl of each half
// owns features (2hl, 2hl+1) as f32 accumulators -> NO cross-lane feature
// reduction; only a 5-level shfl_xor on the final folded scalar.
// Each gather load = 32 lanes x 4B = one 128B row-line PER HALF (2 lines/instr).
// R3 change: loads clustered in 16-deep batches BEFORE any consuming add
// (R2 interleaved 8-load/8-add chunks -> in-order issue capped depth at 8).
// ~32 lines in flight per wave. Clamped slots re-read a hot line, value-masked.
#define AGG_NPB 32
__global__ __launch_bounds__(256) void agg1_kernel(const _Float16* __restrict__ t,
                                                   const int2* __restrict__ row2,
                                                   const int* __restrict__ csr,
                                                   const float* __restrict__ dinv,
                                                   const float* __restrict__ b1,
                                                   const float* __restrict__ w2l,
                                                   float* __restrict__ q, int N) {
    int lane = threadIdx.x & 63;
    int w = threadIdx.x >> 6;
    int hl = lane & 31;    // lane within half
    int hsel = lane >> 5;  // 0 = node A, 1 = node B
    float2 b1v = reinterpret_cast<const float2*>(b1)[hl];
    float2 wlv = reinterpret_cast<const float2*>(w2l)[hl];
    int i0 = blockIdx.x * AGG_NPB;
    int iend = min(i0 + AGG_NPB, N);
    for (int ip = i0 + 2 * w; ip < iend; ip += 8) {
        int iA = ip;
        int iB = ip + 1;  // may be >= iend (tail) -> degB forced to 0
        bool hasB = iB < iend;
        int2 rrA = row2[iA];
        int2 rrB = hasB ? row2[iB] : make_int2(rrA.x, rrA.x);
        int myi = hsel ? iB : iA;
        int myic = min(myi, N - 1);
        int rs = hsel ? rrB.x : rrA.x;
        int re = hsel ? rrB.y : rrA.y;
        int deg = re - rs;
        int kmax = max(rrA.y - rrA.x, rrB.y - rrB.x);
        int rlast = max(re - 1, rs);
        // self loop (features 2hl, 2hl+1 of own row)
        h2 sv = *reinterpret_cast<const h2*>(t + ((size_t)myic << 6) + (hl << 1));
        float a0 = (float)sv[0];
        float a1 = (float)sv[1];
        for (int base = 0; base < kmax; base += 32) {
            // splat up to 32 edge ids of this half's node (coalesced, clamped)
            int sp = min(csr[min(rs + base + hl, rlast)] & 0x1FFFF, N - 1);
            int kend = min(kmax - base, 32);
            {
                h2 vv[16];
#pragma unroll
                for (int j = 0; j < 16; j++) {
                    int s = __shfl(sp, j, 32);  // within-half broadcast
                    vv[j] = *reinterpret_cast<const h2*>(t + ((size_t)s << 6) + (hl << 1));
                }
#pragma unroll
                for (int j = 0; j < 16; j++) {
                    if (base + j < deg) {
                        a0 += (float)vv[j][0];
                        a1 += (float)vv[j][1];
                    }
                }
            }
            if (kend > 16) {
                h2 vv[16];
#pragma unroll
                for (int j = 0; j < 16; j++) {
                    int s = __shfl(sp, 16 + j, 32);
                    vv[j] = *reinterpret_cast<const h2*>(t + ((size_t)s << 6) + (hl << 1));
                }
#pragma unroll
                for (int j = 0; j < 16; j++) {
                    if (base + 16 + j < deg) {
                        a0 += (float)vv[j][0];
                        a1 += (float)vv[j][1];
                    }
                }
            }
        }
        float di = dinv[myic];
        float h0 = fmaxf(di * a0 + b1v.x, 0.f);
        float h1 = fmaxf(di * a1 + b1v.y, 0.f);
        float p = h0 * wlv.x + h1 * wlv.y;
        p += __shfl_xor(p, 1, 64);
        p += __shfl_xor(p, 2, 64);
        p += __shfl_xor(p, 4, 64);
        p += __shfl_xor(p, 8, 64);
        p += __shfl_xor(p, 16, 64);
        if (hl == 0 && myi < iend) q[myi] = di * p;
    }
}

// ===== Layer-2 scalar agg + pooled sum + node counts (batch sorted -> LDS bins) =====
// R3: q-gather unrolled 4-deep (clamped ids, value-masked) -> 4 lines in flight
// per lane instead of 1. Also accumulates per-graph node counts (gcnt) here so
// out_kernel needs no binary search.
__global__ __launch_bounds__(256) void agg2_pool_kernel(const float* __restrict__ q,
                                                        const int2* __restrict__ row2,
                                                        const int* __restrict__ csr,
                                                        const float* __restrict__ dinv,
                                                        const int* __restrict__ batch,
                                                        float* __restrict__ gsum,
                                                        float* __restrict__ gcnt, int N) {
    __shared__ float bins[256];
    __shared__ float cbins[256];
    bins[threadIdx.x] = 0.0f;
    cbins[threadIdx.x] = 0.0f;
    __syncthreads();
    int i = blockIdx.x * 256 + threadIdx.x;
    if (i < N) {
        int2 rr = row2[i];
        int rs = rr.x, re = rr.y;
        float acc = q[i];  // self loop
        int rl = max(re - 1, rs);
        for (int j = rs; j < re; j += 4) {
            int e0 = csr[j];
            int e1 = csr[min(j + 1, rl)];
            int e2 = csr[min(j + 2, rl)];
            int e3 = csr[min(j + 3, rl)];
            float v0 = q[e0];
            float v1 = q[e1];
            float v2 = q[e2];
            float v3 = q[e3];
            acc += v0;
            if (j + 1 < re) acc += v1;
            if (j + 2 < re) acc += v2;
            if (j + 3 < re) acc += v3;
        }
        int g = batch[i];
        atomicAdd(&bins[g], dinv[i] * acc);
        atomicAdd(&cbins[g], 1.0f);
    }
    __syncthreads();
    int i0 = blockIdx.x * 256;
    if (i0 < N) {
        int ilast = min(i0 + 255, N - 1);
        int gmin = batch[i0];
        int gmax = batch[ilast];
        for (int g = gmin + (int)threadIdx.x; g <= gmax; g += 256) {
            atomicAdd(&gsum[g], bins[g]);
            atomicAdd(&gcnt[g], cbins[g]);
        }
    }
}

// ---- out[g] = gsum[g]/cnt[g] + dot(b2,Wl) + bl ; cnt precomputed in agg2 ----
__global__ void out_kernel(const float* __restrict__ gsum, const float* __restrict__ gcnt,
                           const float* __restrict__ b2, const float* __restrict__ Wl,
                           const float* __restrict__ bl, float* __restrict__ out) {
    int g = threadIdx.x;
    // dot(b2, Wl) via lane-parallel partial + 6-level reduce (lanes 0-63 of wave 0..3 identical)
    int lane = g & 63;
    float c = b2[lane] * Wl[lane];
    c += __shfl_xor(c, 1, 64);
    c += __shfl_xor(c, 2, 64);
    c += __shfl_xor(c, 4, 64);
    c += __shfl_xor(c, 8, 64);
    c += __shfl_xor(c, 16, 64);
    c += __shfl_xor(c, 32, 64);
    out[g] = gsum[g] / fmaxf(gcnt[g], 1.0f) + c + bl[0];
}

extern "C" void kernel_launch(void* const* d_in, const int* in_sizes, int n_in,
                              void* d_out, int out_size, void* d_ws, size_t ws_size,
                              hipStream_t stream) {
    const float* x  = (const float*)d_in[0];
    const int*   ei = (const int*)d_in[1];
    const int*   batch = (const int*)d_in[2];
    const float* W1 = (const float*)d_in[3];
    const float* b1 = (const float*)d_in[4];
    const float* W2 = (const float*)d_in[5];
    const float* b2 = (const float*)d_in[6];
    const float* Wl = (const float*)d_in[7];
    const float* bl = (const float*)d_in[8];
    float* out = (float*)d_out;

    const int N = N_NODES, E = N_EDGES;
    const int nblk = (N + 255) / 256;  // 391
    const int* src = ei;
    const int* dst = ei + E;

    // workspace layout (bytes; big aligned blocks first)
    char* ws = (char*)d_ws;
    int*      ebuf      = (int*)ws;       ws += (size_t)R_BUCKETS * CAP * 4;  // 8.4 MB (packed)
    int*      csr       = (int*)ws;       ws += (size_t)R_BUCKETS * CAP * 4;  // 8.4 MB
    _Float16* buf1      = (_Float16*)ws;  ws += 6400000 * 2;                  // t1 (fp16)
    int2*     row2      = (int2*)ws;      ws += 100096 * 8;
    float*    dinv      = (float*)ws;     ws += 100096 * 4;
    float*    q         = (float*)ws;     ws += 100096 * 4;
    float*    gsum      = (float*)ws;     ws += 256 * 4;   // \ memset'd
    int*      bucket_alloc = (int*)ws;    ws += 256 * 4;   //  | together
    float*    gcnt      = (float*)ws;     ws += 256 * 4;   // /  (3072 B)
    float*    w2l       = (float*)ws;     ws += 256 * 4;
    _Float16* whi       = (_Float16*)ws;  ws += 8192 * 2;
    _Float16* wlo       = (_Float16*)ws;  ws += 8192 * 2;

    hipMemsetAsync(gsum, 0, 3072, stream);  // gsum + bucket_alloc + gcnt (adjacent)

    // CSR build: segmented bucket scatter -> per-bucket build (256 blocks, no global scan)
    bkt_scatter<<<NC, 256, 0, stream>>>(src, dst, bucket_alloc, ebuf, E);
    bkt_build<<<R_BUCKETS, 256, 0, stream>>>(ebuf, bucket_alloc, row2, dinv, csr, N);

    prep_kernel<<<33, 256, 0, stream>>>(W1, W2, Wl, w2l, whi, wlo);

    // Layer 1 GEMM on matrix cores: t1 = fp16(dinv*(x@W1))
    gemm_mfma<<<(N + 127) / 128, 256, 0, stream>>>(x, whi, wlo, dinv, buf1, N);

    // Layer-1 aggregation fused with folded layer-2 GEMM -> scalar q per node
    agg1_kernel<<<(N + AGG_NPB - 1) / AGG_NPB, 256, 0, stream>>>(
        buf1, row2, csr, dinv, b1, w2l, q, N);

    // Layer-2 scalar aggregation + mean-pool numerator + per-graph counts
    agg2_pool_kernel<<<nblk, 256, 0, stream>>>(q, row2, csr, dinv, batch, gsum, gcnt, N);

    out_kernel<<<1, 256, 0, stream>>>(gsum, gcnt, b2, Wl, bl, out);
}